// Round 10
// baseline (253.026 us; speedup 1.0000x reference)
//
#include <hip/hip_runtime.h>

typedef unsigned short u16;
typedef unsigned int u32;
typedef __attribute__((ext_vector_type(8))) __bf16 bf16x8;
typedef __attribute__((ext_vector_type(4))) float floatx4;
typedef const __attribute__((address_space(1))) unsigned char glob_u8;
typedef __attribute__((address_space(3))) unsigned char lds_u8;

#define DEV __device__ __forceinline__

DEV u16 f2bf(float f) {
  return __builtin_bit_cast(u16, (__bf16)f);   // v_cvt (RNE) == manual round-to-nearest-even
}
DEV float bf2f(u16 h) {
  u32 u = ((u32)h) << 16;
  return __builtin_bit_cast(float, u);
}
DEV floatx4 MFMA(bf16x8 a, bf16x8 b, floatx4 c) {
  return __builtin_amdgcn_mfma_f32_16x16x32_bf16(a, b, c, 0, 0, 0);
}

// ---------------- convert: x/weights -> bf16 in MFMA-fragment-tile order -----
// xA: 256 tiles (rb 0..31, kb 0..7), tile = 4096 u16 laid [r4][q][l15][e]
//     element (row = rb*128 + r4*16 + l15, k = kb*32 + q*8 + e)
// WB: 256 tiles (nb 0..31, kb 0..7), tile = 2048 u16 laid [n4][q][l15][e]
//     element (n = nb*64 + g*16 + l15, k = kb*32 + q*8 + e), B[n][k] = W[k][n]
// WoF: 128 tiles (nb32 0..7, kb 0..15), tile = 1024 u16 laid [n2][q][l15][e]
//     element (n = nb32*32 + g*16 + l15, k = kb*32 + q*8 + e), B[n][k] = Wo[k][n]
__global__ void convert_k(const float* __restrict__ x, const float* __restrict__ Wq,
                          const float* __restrict__ Wkv, const float* __restrict__ Wg,
                          const float* __restrict__ Wo,
                          u16* __restrict__ xA, u16* __restrict__ WB, u16* __restrict__ WoF) {
  int i = blockIdx.x * 256 + threadIdx.x;
  if (i < 131072) {           // xA chunks (8 u16 each)
    int tile = i >> 9, w = i & 511;
    int g = w >> 6, q = (w >> 4) & 3, l15 = w & 15;
    int rb = tile >> 3, kb = tile & 7;
    int row = rb * 128 + g * 16 + l15;
    int k0 = kb * 32 + q * 8;
    float4 v0 = *(const float4*)(x + row * 256 + k0);
    float4 v1 = *(const float4*)(x + row * 256 + k0 + 4);
    u16 o[8] = {f2bf(v0.x), f2bf(v0.y), f2bf(v0.z), f2bf(v0.w),
                f2bf(v1.x), f2bf(v1.y), f2bf(v1.z), f2bf(v1.w)};
    *(uint4*)(xA + (size_t)i * 8) = *(uint4*)o;
    return;
  }
  i -= 131072;
  if (i < 65536) {            // WB chunks
    int tile = i >> 8, w = i & 255;
    int g = (w >> 6) & 3, q = (w >> 4) & 3, l15 = w & 15;
    int nb = tile >> 3, kb = tile & 7;
    int n = nb * 64 + g * 16 + l15;
    int k0 = kb * 32 + q * 8;
    u16 o[8];
#pragma unroll
    for (int e = 0; e < 8; ++e) {
      int k = k0 + e;
      float v;
      if (n < 512) v = Wq[k * 512 + n];
      else if (n < 1536) v = Wkv[k * 1024 + (n - 512)];
      else v = Wg[k * 512 + (n - 1536)];
      o[e] = f2bf(v);
    }
    *(uint4*)(WB + (size_t)i * 8) = *(uint4*)o;
    return;
  }
  i -= 65536;
  if (i < 16384) {            // WoF chunks
    int tile = i >> 7, w = i & 127;
    int g = (w >> 6) & 1, q = (w >> 4) & 3, l15 = w & 15;
    int nb32 = tile >> 4, kb = tile & 15;
    int n = nb32 * 32 + g * 16 + l15;
    int k0 = kb * 32 + q * 8;
    u16 o[8];
#pragma unroll
    for (int e = 0; e < 8; ++e) o[e] = f2bf(Wo[(k0 + e) * 256 + n]);
    *(uint4*)(WoF + (size_t)i * 8) = *(uint4*)o;
  }
}

// -------- GEMM1: 128x64 tiles, DMA-staged frag-order operands, dbuf ----------
// (unchanged from round 6 -- proven -5 us)
__global__ __launch_bounds__(256, 4) void gemm_qkvg(
    const u16* __restrict__ xA, const u16* __restrict__ WB, const float* __restrict__ bg,
    u16* __restrict__ qb, u16* __restrict__ kfrag, u16* __restrict__ vfrag, u16* __restrict__ gb) {
  __shared__ __attribute__((aligned(16))) u16 As[2][4096];   // 2 x 8 KB A frag-tiles
  __shared__ __attribute__((aligned(16))) u16 Bs[2][2048];   // 2 x 4 KB B frag-tiles
  const int tid = threadIdx.x;
  const int wave = tid >> 6, lane = tid & 63;
  const int lane15 = lane & 15, quad = lane >> 4;
  const int rb = blockIdx.x;            // 128-row block
  const int nb = blockIdx.y;            // 64-col block
  const int rm0 = rb * 128;
  const int cn0 = nb * 64;
  const int wm = (wave & 1) * 64, wn = (wave >> 1) * 32;
  const int ga = (wave & 1) * 4;        // A fragment-group base for this wave
  const int gb2 = (wave >> 1) * 2;      // B fragment-group base for this wave

  floatx4 acc[4][2] = {};

  auto stage = [&](int kb, int bufi) {
    const u16* At = xA + ((size_t)(rb * 8 + kb)) * 4096;
    const u16* Bt = WB + ((size_t)(nb * 8 + kb)) * 2048;
#pragma unroll
    for (int c = 0; c < 2; ++c) {
      int ch = wave * 2 + c;
      __builtin_amdgcn_global_load_lds((glob_u8*)(At + ch * 512 + lane * 8),
                                       (lds_u8*)(&As[bufi][ch * 512]), 16, 0, 0);
    }
    __builtin_amdgcn_global_load_lds((glob_u8*)(Bt + wave * 512 + lane * 8),
                                     (lds_u8*)(&Bs[bufi][wave * 512]), 16, 0, 0);
  };

  stage(0, 0);
  __syncthreads();   // implicit vmcnt(0): tile 0 resident
  int cur = 0;
#pragma unroll 1
  for (int kb = 0; kb < 8; ++kb) {
    if (kb < 7) stage(kb + 1, cur ^ 1);   // prefetch overlaps compute
    const u16* Ac = As[cur];
    const u16* Bc = Bs[cur];
    bf16x8 af[4], bfr[2];
#pragma unroll
    for (int mt = 0; mt < 4; ++mt) af[mt] = *(const bf16x8*)(Ac + ((ga + mt) * 64 + lane) * 8);
#pragma unroll
    for (int nt = 0; nt < 2; ++nt) bfr[nt] = *(const bf16x8*)(Bc + ((gb2 + nt) * 64 + lane) * 8);
#pragma unroll
    for (int mt = 0; mt < 4; ++mt)
#pragma unroll
      for (int nt = 0; nt < 2; ++nt)
        acc[mt][nt] = MFMA(af[mt], bfr[nt], acc[mt][nt]);
    __syncthreads();   // drains prefetch + protects buf reuse
    cur ^= 1;
  }
#pragma unroll
  for (int mt = 0; mt < 4; ++mt)
#pragma unroll
    for (int nt = 0; nt < 2; ++nt)
#pragma unroll
      for (int r = 0; r < 4; ++r) {
        int row = rm0 + wm + mt * 16 + quad * 4 + r;
        int col = cn0 + wn + nt * 16 + lane15;
        float v = acc[mt][nt][r];
        int b = row >> 10, n = row & 1023;
        if (col < 512) {
          int h = col >> 6, d = col & 63;
          qb[((b * 8 + h) * 1024 + n) * 64 + d] = f2bf(v * 0.125f);
        } else if (col < 1024) {
          int c = col - 512, h = c >> 6, d = c & 63;
          int bh2 = b * 8 + h;
          int t = n >> 4, l15 = n & 15;
          int half = d >> 5, qd = (d >> 3) & 3, e = d & 7;
          kfrag[(size_t)bh2 * 65536 + t * 1024 + half * 512 + (qd * 16 + l15) * 8 + e] = f2bf(v);
        } else if (col < 1536) {
          int c = col - 1024, h = c >> 6, d = c & 63;
          int bh2 = b * 8 + h;
          int t64 = n >> 6, ck = (n >> 5) & 1, qd = (n >> 3) & 3, e = n & 7;
          int dt = d >> 4, l15 = d & 15;
          vfrag[(size_t)bh2 * 65536 + t64 * 4096 + dt * 1024 + ck * 512 + (qd * 16 + l15) * 8 + e] = f2bf(v);
        } else {
          int c = col - 1536;
          float g = 1.0f / (1.0f + __expf(-(v + bg[c])));
          gb[row * 512 + c] = f2bf(g);
        }
      }
}

// ------- fused attention: 32 q-rows/block; K-step 128 (2 key-tiles/buffer) ---
// 8 barrier-pairs instead of 16 (R9's proven barrier-amortization mechanism).
// LDS 69 KB -> 2 blocks/CU (R5 proved 2 vs 4 blocks/CU neutral here).
__global__ __launch_bounds__(256, 2) void attn_k(
    const u16* __restrict__ qb, const u16* __restrict__ kfrag, const u16* __restrict__ vfrag,
    const float* __restrict__ bias, const u16* __restrict__ gb, u16* __restrict__ ogf) {
  __shared__ __attribute__((aligned(16))) u16 Kt[2][8192];   // 2 buf x 2 key-tiles (16 KB)
  __shared__ __attribute__((aligned(16))) u16 Vt[2][8192];   // 2 buf x 2 key-tiles (16 KB)
  __shared__ __attribute__((aligned(16))) u16 Ps[4 * 16 * 40];
  const int tid = threadIdx.x;
  const int wave = tid >> 6, lane = tid & 63;
  const int lane15 = lane & 15, quad = lane >> 4;
  const int bh = blockIdx.x;
  const int q0 = blockIdx.y * 32;
  const int qw = (wave & 1) * 16;   // wave's q-sub-tile
  const int kh = wave >> 1;         // wave's 32-key half of each 64-key tile

  bf16x8 qf0, qf1;
  {
    const u16* qrow = qb + ((size_t)(bh * 1024 + q0 + qw + lane15)) * 64 + quad * 8;
    qf0 = *(const bf16x8*)(qrow);
    qf1 = *(const bf16x8*)(qrow + 32);
  }
  bf16x8 ones;
#pragma unroll
  for (int e = 0; e < 8; ++e) ones[e] = __builtin_bit_cast(__bf16, (u16)0x3F80);

  floatx4 oacc[4] = {};
  floatx4 lacc = {};

  u16* Pw = Ps + wave * (16 * 40);
  const u16* kp = kfrag + (size_t)bh * 65536;
  const u16* vp = vfrag + (size_t)bh * 65536;
  const float* bbase = bias + ((size_t)(bh * 1024 + q0 + qw + quad * 4)) * 1024 + kh * 32 + lane15;

  // ---- stage two consecutive 64-key K/V tiles (contiguous) -> buffer bufi ----
  auto stage = [&](int ks, int bufi) {
    const u16* kS = kp + ks * 8192;
    const u16* vS = vp + ks * 8192;
#pragma unroll
    for (int c = 0; c < 4; ++c) {
      int ch = wave * 4 + c;
      __builtin_amdgcn_global_load_lds((glob_u8*)(kS + ch * 512 + lane * 8),
                                       (lds_u8*)(&Kt[bufi][ch * 512]), 16, 0, 0);
      __builtin_amdgcn_global_load_lds((glob_u8*)(vS + ch * 512 + lane * 8),
                                       (lds_u8*)(&Vt[bufi][ch * 512]), 16, 0, 0);
    }
  };

  stage(0, 0);
  __syncthreads();   // implicit vmcnt(0): step 0 resident
  int cur = 0;
#pragma unroll 1
  for (int ks = 0; ks < 8; ++ks) {
    if (ks < 7) stage(ks + 1, cur ^ 1);   // prefetch overlaps 2-tile compute
#pragma unroll
    for (int kk = 0; kk < 2; ++kk) {
      const int kt = ks * 2 + kk;
      const u16* Ktc = Kt[cur] + kk * 4096;
      const u16* Vtc = Vt[cur] + kk * 4096;
      float bv[4][2];
#pragma unroll
      for (int r = 0; r < 4; ++r)
#pragma unroll
        for (int j = 0; j < 2; ++j)
          bv[r][j] = bbase[r * 1024 + kt * 64 + j * 16];
      floatx4 s[2];
#pragma unroll
      for (int j = 0; j < 2; ++j) {
        const u16* kb = Ktc + (kh * 2 + j) * 1024 + lane * 8;
        bf16x8 kf0 = *(const bf16x8*)(kb);
        bf16x8 kf1 = *(const bf16x8*)(kb + 512);
        floatx4 z = {};
        z = MFMA(qf0, kf0, z);
        s[j] = MFMA(qf1, kf1, z);
      }
#pragma unroll
      for (int j = 0; j < 2; ++j)
#pragma unroll
        for (int r = 0; r < 4; ++r)
          s[j][r] = __expf(s[j][r] + bv[r][j] - 8.0f);
#pragma unroll
      for (int j = 0; j < 2; ++j)
#pragma unroll
        for (int r = 0; r < 4; ++r)
          Pw[(quad * 4 + r) * 40 + j * 16 + lane15] = f2bf(s[j][r]);
      bf16x8 pf = *(const bf16x8*)(Pw + lane15 * 40 + quad * 8);

      lacc = MFMA(pf, ones, lacc);
#pragma unroll
      for (int dt = 0; dt < 4; ++dt) {
        bf16x8 vf = *(const bf16x8*)(Vtc + dt * 1024 + kh * 512 + lane * 8);
        oacc[dt] = MFMA(pf, vf, oacc[dt]);
      }
    }
    __syncthreads();   // drains prefetch (vmcnt(0)) + protects buf reuse
    cur ^= 1;
  }

  float* red = (float*)Kt;
  if (wave >= 2) {
    float* r0 = red + (wave - 2) * 1280 + lane * 20;
#pragma unroll
    for (int dt = 0; dt < 4; ++dt)
#pragma unroll
      for (int r = 0; r < 4; ++r) r0[dt * 4 + r] = oacc[dt][r];
#pragma unroll
    for (int r = 0; r < 4; ++r) r0[16 + r] = lacc[r];
  }
  __syncthreads();
  if (wave < 2) {
    const float* r0 = red + wave * 1280 + lane * 20;
#pragma unroll
    for (int dt = 0; dt < 4; ++dt)
#pragma unroll
      for (int r = 0; r < 4; ++r) oacc[dt][r] += r0[dt * 4 + r];
#pragma unroll
    for (int r = 0; r < 4; ++r) lacc[r] += r0[16 + r];

    // ---- fused epilogue: normalize, gate, write ogf (gemm2 A-frag order) ----
    const int b = bh >> 3, h = bh & 7;
#pragma unroll
    for (int r = 0; r < 4; ++r) {
      int q = q0 + wave * 16 + quad * 4 + r;
      int row = b * 1024 + q;
      float inv = 1.0f / lacc[r];
      int rb64 = row >> 6, g = (row >> 4) & 3, l15r = row & 15;
#pragma unroll
      for (int dt = 0; dt < 4; ++dt) {
        int k = h * 64 + dt * 16 + lane15;
        size_t gi = ((size_t)row) * 512 + k;          // gate, old layout
        int kb = k >> 5, qf = (k >> 3) & 3, e = k & 7;
        ogf[((size_t)(rb64 * 16 + kb)) * 2048 + ((g * 4 + qf) * 16 + l15r) * 8 + e] =
            f2bf(oacc[dt][r] * inv * bf2f(gb[gi]));
      }
    }
  }
}

// ------- GEMM2: 64x32 tiles, DMA-staged frag-order, K-step 64, dbuf ----------
// (unchanged from round 9 -- proven -2.5 us)
__global__ __launch_bounds__(256, 4) void gemm_out_k(
    const u16* __restrict__ ogf, const u16* __restrict__ WoF,
    const float* __restrict__ bo, float* __restrict__ out) {
  __shared__ __attribute__((aligned(16))) u16 As[2][4096];   // 2 x (2 kb-tiles x 2048)
  __shared__ __attribute__((aligned(16))) u16 Bs[2][2048];   // 2 x (2 kb-tiles x 1024)
  const int tid = threadIdx.x;
  const int wave = tid >> 6, lane = tid & 63;
  const int lane15 = lane & 15, quad = lane >> 4;
  const int rb = blockIdx.x;    // 64-row block (0..63)
  const int nb = blockIdx.y;    // 32-col block (0..7)
  const int ga = (wave & 1) * 2;      // A fragment-group base (rows wm..wm+31)
  const int gbb = wave >> 1;          // B fragment-group (cols wn..wn+15)

  floatx4 acc[2] = {};

  auto stage = [&](int ks, int bufi) {   // stages kb = 2*ks, 2*ks+1 (contiguous)
    const u16* At = ogf + ((size_t)(rb * 16 + ks * 2)) * 2048;   // 4096 u16 contiguous
    const u16* Bt = WoF + ((size_t)(nb * 16 + ks * 2)) * 1024;   // 2048 u16 contiguous
#pragma unroll
    for (int c = 0; c < 2; ++c) {
      int ch = wave * 2 + c;
      __builtin_amdgcn_global_load_lds((glob_u8*)(At + ch * 512 + lane * 8),
                                       (lds_u8*)(&As[bufi][ch * 512]), 16, 0, 0);
    }
    __builtin_amdgcn_global_load_lds((glob_u8*)(Bt + wave * 512 + lane * 8),
                                     (lds_u8*)(&Bs[bufi][wave * 512]), 16, 0, 0);
  };

  stage(0, 0);
  __syncthreads();   // implicit vmcnt(0): step 0 resident
  int cur = 0;
#pragma unroll 1
  for (int ks = 0; ks < 8; ++ks) {
    if (ks < 7) stage(ks + 1, cur ^ 1);   // prefetch overlaps compute
    const u16* Ac = As[cur];
    const u16* Bc = Bs[cur];
#pragma unroll
    for (int kk = 0; kk < 2; ++kk) {
      bf16x8 af[2];
#pragma unroll
      for (int mt = 0; mt < 2; ++mt)
        af[mt] = *(const bf16x8*)(Ac + kk * 2048 + ((ga + mt) * 64 + lane) * 8);
      bf16x8 bfr = *(const bf16x8*)(Bc + kk * 1024 + (gbb * 64 + lane) * 8);
#pragma unroll
      for (int mt = 0; mt < 2; ++mt) acc[mt] = MFMA(af[mt], bfr, acc[mt]);
    }
    __syncthreads();   // drains prefetch + protects buf reuse
    cur ^= 1;
  }
  const int col = nb * 32 + gbb * 16 + lane15;
  const float bv = bo[col];
#pragma unroll
  for (int mt = 0; mt < 2; ++mt)
#pragma unroll
    for (int r = 0; r < 4; ++r) {
      int row = rb * 64 + (wave & 1) * 32 + mt * 16 + quad * 4 + r;
      out[(size_t)row * 256 + col] = acc[mt][r] + bv;
    }
}

extern "C" void kernel_launch(void* const* d_in, const int* in_sizes, int n_in,
                              void* d_out, int out_size, void* d_ws, size_t ws_size,
                              hipStream_t stream) {
  const float* x = (const float*)d_in[0];
  const float* bias = (const float*)d_in[1];
  const float* Wq = (const float*)d_in[2];
  const float* Wkv = (const float*)d_in[3];
  const float* Wo = (const float*)d_in[4];
  const float* bo = (const float*)d_in[5];
  const float* Wg = (const float*)d_in[6];
  const float* bg = (const float*)d_in[7];
  float* out = (float*)d_out;
  char* ws = (char*)d_ws;
  u16* xA    = (u16*)(ws);                 // 2 MB (frag-tile order)
  u16* WB    = (u16*)(ws + 2097152);       // 1 MB (frag-tile order)
  u16* WoF   = (u16*)(ws + 3145728);       // 256 KB (frag-tile order)
  u16* qb    = (u16*)(ws + 3407872);       // 4 MB
  u16* kfrag = (u16*)(ws + 7602176);       // 4 MB
  u16* vfrag = (u16*)(ws + 11796480);      // 4 MB
  u16* gb    = (u16*)(ws + 15990784);      // 4 MB
  u16* ogf   = (u16*)(ws + 20185088);      // 4 MB (frag-tile order)

  convert_k<<<832, 256, 0, stream>>>(x, Wq, Wkv, Wg, Wo, xA, WB, WoF);
  dim3 g1(32, 32);
  gemm_qkvg<<<g1, 256, 0, stream>>>(xA, WB, bg, qb, kfrag, vfrag, gb);
  dim3 g2(32, 32);
  attn_k<<<g2, 256, 0, stream>>>(qb, kfrag, vfrag, bias, gb, ogf);
  dim3 g3(64, 8);
  gemm_out_k<<<g3, 256, 0, stream>>>(ogf, WoF, bo, out);
}

// Round 11
// 247.506 us; speedup vs baseline: 1.0223x; 1.0223x over previous
//
#include <hip/hip_runtime.h>

typedef unsigned short u16;
typedef unsigned int u32;
typedef __attribute__((ext_vector_type(8))) __bf16 bf16x8;
typedef __attribute__((ext_vector_type(4))) float floatx4;
typedef const __attribute__((address_space(1))) unsigned char glob_u8;
typedef __attribute__((address_space(3))) unsigned char lds_u8;

#define DEV __device__ __forceinline__

DEV u16 f2bf(float f) {
  return __builtin_bit_cast(u16, (__bf16)f);   // v_cvt (RNE) == manual round-to-nearest-even
}
DEV float bf2f(u16 h) {
  u32 u = ((u32)h) << 16;
  return __builtin_bit_cast(float, u);
}
DEV floatx4 MFMA(bf16x8 a, bf16x8 b, floatx4 c) {
  return __builtin_amdgcn_mfma_f32_16x16x32_bf16(a, b, c, 0, 0, 0);
}

// ---------------- convert: x/weights -> bf16 in MFMA-fragment-tile order -----
// xA: 256 tiles (rb 0..31, kb 0..7), tile = 4096 u16 laid [r4][q][l15][e]
//     element (row = rb*128 + r4*16 + l15, k = kb*32 + q*8 + e)
// WB: 256 tiles (nb 0..31, kb 0..7), tile = 2048 u16 laid [n4][q][l15][e]
//     element (n = nb*64 + g*16 + l15, k = kb*32 + q*8 + e), B[n][k] = W[k][n]
// WoF: 128 tiles (nb32 0..7, kb 0..15), tile = 1024 u16 laid [n2][q][l15][e]
//     element (n = nb32*32 + g*16 + l15, k = kb*32 + q*8 + e), B[n][k] = Wo[k][n]
__global__ void convert_k(const float* __restrict__ x, const float* __restrict__ Wq,
                          const float* __restrict__ Wkv, const float* __restrict__ Wg,
                          const float* __restrict__ Wo,
                          u16* __restrict__ xA, u16* __restrict__ WB, u16* __restrict__ WoF) {
  int i = blockIdx.x * 256 + threadIdx.x;
  if (i < 131072) {           // xA chunks (8 u16 each)
    int tile = i >> 9, w = i & 511;
    int g = w >> 6, q = (w >> 4) & 3, l15 = w & 15;
    int rb = tile >> 3, kb = tile & 7;
    int row = rb * 128 + g * 16 + l15;
    int k0 = kb * 32 + q * 8;
    float4 v0 = *(const float4*)(x + row * 256 + k0);
    float4 v1 = *(const float4*)(x + row * 256 + k0 + 4);
    u16 o[8] = {f2bf(v0.x), f2bf(v0.y), f2bf(v0.z), f2bf(v0.w),
                f2bf(v1.x), f2bf(v1.y), f2bf(v1.z), f2bf(v1.w)};
    *(uint4*)(xA + (size_t)i * 8) = *(uint4*)o;
    return;
  }
  i -= 131072;
  if (i < 65536) {            // WB chunks
    int tile = i >> 8, w = i & 255;
    int g = (w >> 6) & 3, q = (w >> 4) & 3, l15 = w & 15;
    int nb = tile >> 3, kb = tile & 7;
    int n = nb * 64 + g * 16 + l15;
    int k0 = kb * 32 + q * 8;
    u16 o[8];
#pragma unroll
    for (int e = 0; e < 8; ++e) {
      int k = k0 + e;
      float v;
      if (n < 512) v = Wq[k * 512 + n];
      else if (n < 1536) v = Wkv[k * 1024 + (n - 512)];
      else v = Wg[k * 512 + (n - 1536)];
      o[e] = f2bf(v);
    }
    *(uint4*)(WB + (size_t)i * 8) = *(uint4*)o;
    return;
  }
  i -= 65536;
  if (i < 16384) {            // WoF chunks
    int tile = i >> 7, w = i & 127;
    int g = (w >> 6) & 1, q = (w >> 4) & 3, l15 = w & 15;
    int nb32 = tile >> 4, kb = tile & 15;
    int n = nb32 * 32 + g * 16 + l15;
    int k0 = kb * 32 + q * 8;
    u16 o[8];
#pragma unroll
    for (int e = 0; e < 8; ++e) o[e] = f2bf(Wo[(k0 + e) * 256 + n]);
    *(uint4*)(WoF + (size_t)i * 8) = *(uint4*)o;
  }
}

// -------- GEMM1: 128x64 tiles, DMA-staged frag-order operands, dbuf ----------
// (round 6 config -- proven -5 us)
__global__ __launch_bounds__(256, 4) void gemm_qkvg(
    const u16* __restrict__ xA, const u16* __restrict__ WB, const float* __restrict__ bg,
    u16* __restrict__ qb, u16* __restrict__ kfrag, u16* __restrict__ vfrag, u16* __restrict__ gb) {
  __shared__ __attribute__((aligned(16))) u16 As[2][4096];   // 2 x 8 KB A frag-tiles
  __shared__ __attribute__((aligned(16))) u16 Bs[2][2048];   // 2 x 4 KB B frag-tiles
  const int tid = threadIdx.x;
  const int wave = tid >> 6, lane = tid & 63;
  const int lane15 = lane & 15, quad = lane >> 4;
  const int rb = blockIdx.x;            // 128-row block
  const int nb = blockIdx.y;            // 64-col block
  const int rm0 = rb * 128;
  const int cn0 = nb * 64;
  const int wm = (wave & 1) * 64, wn = (wave >> 1) * 32;
  const int ga = (wave & 1) * 4;        // A fragment-group base for this wave
  const int gb2 = (wave >> 1) * 2;      // B fragment-group base for this wave

  floatx4 acc[4][2] = {};

  auto stage = [&](int kb, int bufi) {
    const u16* At = xA + ((size_t)(rb * 8 + kb)) * 4096;
    const u16* Bt = WB + ((size_t)(nb * 8 + kb)) * 2048;
#pragma unroll
    for (int c = 0; c < 2; ++c) {
      int ch = wave * 2 + c;
      __builtin_amdgcn_global_load_lds((glob_u8*)(At + ch * 512 + lane * 8),
                                       (lds_u8*)(&As[bufi][ch * 512]), 16, 0, 0);
    }
    __builtin_amdgcn_global_load_lds((glob_u8*)(Bt + wave * 512 + lane * 8),
                                     (lds_u8*)(&Bs[bufi][wave * 512]), 16, 0, 0);
  };

  stage(0, 0);
  __syncthreads();   // implicit vmcnt(0): tile 0 resident
  int cur = 0;
#pragma unroll 1
  for (int kb = 0; kb < 8; ++kb) {
    if (kb < 7) stage(kb + 1, cur ^ 1);   // prefetch overlaps compute
    const u16* Ac = As[cur];
    const u16* Bc = Bs[cur];
    bf16x8 af[4], bfr[2];
#pragma unroll
    for (int mt = 0; mt < 4; ++mt) af[mt] = *(const bf16x8*)(Ac + ((ga + mt) * 64 + lane) * 8);
#pragma unroll
    for (int nt = 0; nt < 2; ++nt) bfr[nt] = *(const bf16x8*)(Bc + ((gb2 + nt) * 64 + lane) * 8);
#pragma unroll
    for (int mt = 0; mt < 4; ++mt)
#pragma unroll
      for (int nt = 0; nt < 2; ++nt)
        acc[mt][nt] = MFMA(af[mt], bfr[nt], acc[mt][nt]);
    __syncthreads();   // drains prefetch + protects buf reuse
    cur ^= 1;
  }
#pragma unroll
  for (int mt = 0; mt < 4; ++mt)
#pragma unroll
    for (int nt = 0; nt < 2; ++nt)
#pragma unroll
      for (int r = 0; r < 4; ++r) {
        int row = rm0 + wm + mt * 16 + quad * 4 + r;
        int col = cn0 + wn + nt * 16 + lane15;
        float v = acc[mt][nt][r];
        int b = row >> 10, n = row & 1023;
        if (col < 512) {
          int h = col >> 6, d = col & 63;
          qb[((b * 8 + h) * 1024 + n) * 64 + d] = f2bf(v * 0.125f);
        } else if (col < 1024) {
          int c = col - 512, h = c >> 6, d = c & 63;
          int bh2 = b * 8 + h;
          int t = n >> 4, l15 = n & 15;
          int half = d >> 5, qd = (d >> 3) & 3, e = d & 7;
          kfrag[(size_t)bh2 * 65536 + t * 1024 + half * 512 + (qd * 16 + l15) * 8 + e] = f2bf(v);
        } else if (col < 1536) {
          int c = col - 1024, h = c >> 6, d = c & 63;
          int bh2 = b * 8 + h;
          int t64 = n >> 6, ck = (n >> 5) & 1, qd = (n >> 3) & 3, e = n & 7;
          int dt = d >> 4, l15 = d & 15;
          vfrag[(size_t)bh2 * 65536 + t64 * 4096 + dt * 1024 + ck * 512 + (qd * 16 + l15) * 8 + e] = f2bf(v);
        } else {
          int c = col - 1536;
          float g = 1.0f / (1.0f + __expf(-(v + bg[c])));
          gb[row * 512 + c] = f2bf(g);
        }
      }
}

// ------- fused attention: 32 q-rows/block, grid (32,32)=1024 -> 4 blocks/CU --
// K-step 64, 16 barrier-pairs (R9 config: bias-BW-bound regime; R10 proved
// bigger K-step regresses here -- occupancy & drain-tail dominate).
__global__ __launch_bounds__(256, 4) void attn_k(
    const u16* __restrict__ qb, const u16* __restrict__ kfrag, const u16* __restrict__ vfrag,
    const float* __restrict__ bias, const u16* __restrict__ gb, u16* __restrict__ ogf) {
  __shared__ __attribute__((aligned(16))) u16 Kt[2][4096];   // 2 x 8 KB frag-order keys
  __shared__ __attribute__((aligned(16))) u16 Vt[2][4096];   // 2 x 8 KB frag-order values
  __shared__ __attribute__((aligned(16))) u16 Ps[4 * 16 * 40];
  const int tid = threadIdx.x;
  const int wave = tid >> 6, lane = tid & 63;
  const int lane15 = lane & 15, quad = lane >> 4;
  const int bh = blockIdx.x;
  const int q0 = blockIdx.y * 32;
  const int qw = (wave & 1) * 16;   // wave's q-sub-tile
  const int kh = wave >> 1;         // wave's 32-key half of each 64-key tile

  bf16x8 qf0, qf1;
  {
    const u16* qrow = qb + ((size_t)(bh * 1024 + q0 + qw + lane15)) * 64 + quad * 8;
    qf0 = *(const bf16x8*)(qrow);
    qf1 = *(const bf16x8*)(qrow + 32);
  }
  bf16x8 ones;
#pragma unroll
  for (int e = 0; e < 8; ++e) ones[e] = __builtin_bit_cast(__bf16, (u16)0x3F80);

  floatx4 oacc[4] = {};
  floatx4 lacc = {};

  u16* Pw = Ps + wave * (16 * 40);
  const u16* kp = kfrag + (size_t)bh * 65536;
  const u16* vp = vfrag + (size_t)bh * 65536;
  const float* bbase = bias + ((size_t)(bh * 1024 + q0 + qw + quad * 4)) * 1024 + kh * 32 + lane15;

  auto stage = [&](int kt, int bufi) {
    const u16* kS = kp + kt * 4096;
    const u16* vS = vp + kt * 4096;
#pragma unroll
    for (int c = 0; c < 2; ++c) {
      int ch = wave * 2 + c;
      __builtin_amdgcn_global_load_lds((glob_u8*)(kS + ch * 512 + lane * 8),
                                       (lds_u8*)(&Kt[bufi][ch * 512]), 16, 0, 0);
      __builtin_amdgcn_global_load_lds((glob_u8*)(vS + ch * 512 + lane * 8),
                                       (lds_u8*)(&Vt[bufi][ch * 512]), 16, 0, 0);
    }
  };

  stage(0, 0);
  __syncthreads();
  int cur = 0;
#pragma unroll 1
  for (int kt = 0; kt < 16; ++kt) {
    if (kt < 15) stage(kt + 1, cur ^ 1);
    float bv[4][2];
#pragma unroll
    for (int r = 0; r < 4; ++r)
#pragma unroll
      for (int j = 0; j < 2; ++j)
        bv[r][j] = bbase[r * 1024 + kt * 64 + j * 16];
    const u16* Ktc = Kt[cur];
    const u16* Vtc = Vt[cur];
    floatx4 s[2];
#pragma unroll
    for (int j = 0; j < 2; ++j) {
      const u16* kb = Ktc + (kh * 2 + j) * 1024 + lane * 8;
      bf16x8 kf0 = *(const bf16x8*)(kb);
      bf16x8 kf1 = *(const bf16x8*)(kb + 512);
      floatx4 z = {};
      z = MFMA(qf0, kf0, z);
      s[j] = MFMA(qf1, kf1, z);
    }
#pragma unroll
    for (int j = 0; j < 2; ++j)
#pragma unroll
      for (int r = 0; r < 4; ++r)
        s[j][r] = __expf(s[j][r] + bv[r][j] - 8.0f);
#pragma unroll
    for (int j = 0; j < 2; ++j)
#pragma unroll
      for (int r = 0; r < 4; ++r)
        Pw[(quad * 4 + r) * 40 + j * 16 + lane15] = f2bf(s[j][r]);
    bf16x8 pf = *(const bf16x8*)(Pw + lane15 * 40 + quad * 8);

    lacc = MFMA(pf, ones, lacc);
#pragma unroll
    for (int dt = 0; dt < 4; ++dt) {
      bf16x8 vf = *(const bf16x8*)(Vtc + dt * 1024 + kh * 512 + lane * 8);
      oacc[dt] = MFMA(pf, vf, oacc[dt]);
    }
    __syncthreads();
    cur ^= 1;
  }

  float* red = (float*)Kt;
  if (wave >= 2) {
    float* r0 = red + (wave - 2) * 1280 + lane * 20;
#pragma unroll
    for (int dt = 0; dt < 4; ++dt)
#pragma unroll
      for (int r = 0; r < 4; ++r) r0[dt * 4 + r] = oacc[dt][r];
#pragma unroll
    for (int r = 0; r < 4; ++r) r0[16 + r] = lacc[r];
  }
  __syncthreads();
  if (wave < 2) {
    const float* r0 = red + wave * 1280 + lane * 20;
#pragma unroll
    for (int dt = 0; dt < 4; ++dt)
#pragma unroll
      for (int r = 0; r < 4; ++r) oacc[dt][r] += r0[dt * 4 + r];
#pragma unroll
    for (int r = 0; r < 4; ++r) lacc[r] += r0[16 + r];

    // ---- fused epilogue: normalize, gate, write ogf (gemm2 A-frag order) ----
    const int b = bh >> 3, h = bh & 7;
#pragma unroll
    for (int r = 0; r < 4; ++r) {
      int q = q0 + wave * 16 + quad * 4 + r;
      int row = b * 1024 + q;
      float inv = 1.0f / lacc[r];
      int rb64 = row >> 6, g = (row >> 4) & 3, l15r = row & 15;
#pragma unroll
      for (int dt = 0; dt < 4; ++dt) {
        int k = h * 64 + dt * 16 + lane15;
        size_t gi = ((size_t)row) * 512 + k;          // gate, old layout
        int kb = k >> 5, qf = (k >> 3) & 3, e = k & 7;
        ogf[((size_t)(rb64 * 16 + kb)) * 2048 + ((g * 4 + qf) * 16 + l15r) * 8 + e] =
            f2bf(oacc[dt][r] * inv * bf2f(gb[gi]));
      }
    }
  }
}

// ------- GEMM2: 64x32 tiles, DMA-staged frag-order, K-step 64, dbuf ----------
// (round 9 config -- proven -2.5 us)
__global__ __launch_bounds__(256, 4) void gemm_out_k(
    const u16* __restrict__ ogf, const u16* __restrict__ WoF,
    const float* __restrict__ bo, float* __restrict__ out) {
  __shared__ __attribute__((aligned(16))) u16 As[2][4096];   // 2 x (2 kb-tiles x 2048)
  __shared__ __attribute__((aligned(16))) u16 Bs[2][2048];   // 2 x (2 kb-tiles x 1024)
  const int tid = threadIdx.x;
  const int wave = tid >> 6, lane = tid & 63;
  const int lane15 = lane & 15, quad = lane >> 4;
  const int rb = blockIdx.x;    // 64-row block (0..63)
  const int nb = blockIdx.y;    // 32-col block (0..7)
  const int ga = (wave & 1) * 2;      // A fragment-group base (rows wm..wm+31)
  const int gbb = wave >> 1;          // B fragment-group (cols wn..wn+15)

  floatx4 acc[2] = {};

  auto stage = [&](int ks, int bufi) {   // stages kb = 2*ks, 2*ks+1 (contiguous)
    const u16* At = ogf + ((size_t)(rb * 16 + ks * 2)) * 2048;   // 4096 u16 contiguous
    const u16* Bt = WoF + ((size_t)(nb * 16 + ks * 2)) * 1024;   // 2048 u16 contiguous
#pragma unroll
    for (int c = 0; c < 2; ++c) {
      int ch = wave * 2 + c;
      __builtin_amdgcn_global_load_lds((glob_u8*)(At + ch * 512 + lane * 8),
                                       (lds_u8*)(&As[bufi][ch * 512]), 16, 0, 0);
    }
    __builtin_amdgcn_global_load_lds((glob_u8*)(Bt + wave * 512 + lane * 8),
                                     (lds_u8*)(&Bs[bufi][wave * 512]), 16, 0, 0);
  };

  stage(0, 0);
  __syncthreads();   // implicit vmcnt(0): step 0 resident
  int cur = 0;
#pragma unroll 1
  for (int ks = 0; ks < 8; ++ks) {
    if (ks < 7) stage(ks + 1, cur ^ 1);   // prefetch overlaps compute
    const u16* Ac = As[cur];
    const u16* Bc = Bs[cur];
#pragma unroll
    for (int kk = 0; kk < 2; ++kk) {
      bf16x8 af[2];
#pragma unroll
      for (int mt = 0; mt < 2; ++mt)
        af[mt] = *(const bf16x8*)(Ac + kk * 2048 + ((ga + mt) * 64 + lane) * 8);
      bf16x8 bfr = *(const bf16x8*)(Bc + kk * 1024 + (gbb * 64 + lane) * 8);
#pragma unroll
      for (int mt = 0; mt < 2; ++mt) acc[mt] = MFMA(af[mt], bfr, acc[mt]);
    }
    __syncthreads();   // drains prefetch + protects buf reuse
    cur ^= 1;
  }
  const int col = nb * 32 + gbb * 16 + lane15;
  const float bv = bo[col];
#pragma unroll
  for (int mt = 0; mt < 2; ++mt)
#pragma unroll
    for (int r = 0; r < 4; ++r) {
      int row = rb * 64 + (wave & 1) * 32 + mt * 16 + quad * 4 + r;
      out[(size_t)row * 256 + col] = acc[mt][r] + bv;
    }
}

extern "C" void kernel_launch(void* const* d_in, const int* in_sizes, int n_in,
                              void* d_out, int out_size, void* d_ws, size_t ws_size,
                              hipStream_t stream) {
  const float* x = (const float*)d_in[0];
  const float* bias = (const float*)d_in[1];
  const float* Wq = (const float*)d_in[2];
  const float* Wkv = (const float*)d_in[3];
  const float* Wo = (const float*)d_in[4];
  const float* bo = (const float*)d_in[5];
  const float* Wg = (const float*)d_in[6];
  const float* bg = (const float*)d_in[7];
  float* out = (float*)d_out;
  char* ws = (char*)d_ws;
  u16* xA    = (u16*)(ws);                 // 2 MB (frag-tile order)
  u16* WB    = (u16*)(ws + 2097152);       // 1 MB (frag-tile order)
  u16* WoF   = (u16*)(ws + 3145728);       // 256 KB (frag-tile order)
  u16* qb    = (u16*)(ws + 3407872);       // 4 MB
  u16* kfrag = (u16*)(ws + 7602176);       // 4 MB
  u16* vfrag = (u16*)(ws + 11796480);      // 4 MB
  u16* gb    = (u16*)(ws + 15990784);      // 4 MB
  u16* ogf   = (u16*)(ws + 20185088);      // 4 MB (frag-tile order)

  convert_k<<<832, 256, 0, stream>>>(x, Wq, Wkv, Wg, Wo, xA, WB, WoF);
  dim3 g1(32, 32);
  gemm_qkvg<<<g1, 256, 0, stream>>>(xA, WB, bg, qb, kfrag, vfrag, gb);
  dim3 g2(32, 32);
  attn_k<<<g2, 256, 0, stream>>>(qb, kfrag, vfrag, bias, gb, ogf);
  dim3 g3(64, 8);
  gemm_out_k<<<g3, 256, 0, stream>>>(ogf, WoF, bo, out);
}